// Round 13
// baseline (134.481 us; speedup 1.0000x reference)
//
#include <hip/hip_runtime.h>

// CfC cell, fp16-MFMA implementation.
//   h   = 1.7159*tanh(0.666*(concat(input,hx) @ Wb^T + bb))   [B,1024]
//   ff1 = tanh(h@W1^T+b1), ff2 = tanh(h@W2^T+b2)
//   t   = sigmoid((h@Wa^T+ba)*ts + (h@Wt^T+bt))
//   out = ff1 + t*(ff2-ff1)                                   [B,512]
// Round 13: clean co-residency test. 128x256 tile / 4 waves (2x2; wave =
// 64x128, acc[4][8]) / BK=32 / 48 KB LDS -> 2-3 blocks per CU, with the
// read:MFMA ratio (0.375 b128/MFMA) of the winning r10/r12 core preserved
// (r11's confound removed). Single-barrier K-tile; c1 gates on 8 b-reads,
// b[4..7] read under c1's shadow. r3-verified BK=32 staging+swizzle
// (zero conflicts measured); r9-style bijective XCD maps; fast_tanh.

typedef _Float16 f16;
typedef _Float16 f16x8 __attribute__((ext_vector_type(8)));
typedef _Float16 f16x4 __attribute__((ext_vector_type(4)));
typedef float f32x4 __attribute__((ext_vector_type(4)));

static constexpr int B_ = 16384, IN_ = 256, HID_ = 512, UNITS_ = 1024, CAT_ = 768;

__device__ __forceinline__ void gload_lds16(const void* g, void* l) {
  __builtin_amdgcn_global_load_lds(
      (const __attribute__((address_space(1))) void*)g,
      (__attribute__((address_space(3))) void*)l, 16, 0, 0);
}

__device__ __forceinline__ float fast_tanh(float x) {
  const float e = __expf(2.0f * x);
  return 1.0f - 2.0f / (e + 1.0f);
}

#define MFMA16(a, b, c) __builtin_amdgcn_mfma_f32_16x16x32_f16((a), (b), (c), 0, 0, 0)
#define BARRIER() do { asm volatile("" ::: "memory"); __builtin_amdgcn_s_barrier(); asm volatile("" ::: "memory"); } while (0)

// ---- prep: build x=concat(input,hx) as f16; cast Wb; head-interleave Wh --
// [0,12288) build_x | [12288,13056) Wb | [13056,15104) Wh   (all exact)

__global__ void prep_kernel(const float* __restrict__ inp,
                            const float* __restrict__ hx,
                            const float* __restrict__ Wb,
                            const float* __restrict__ W1,
                            const float* __restrict__ W2,
                            const float* __restrict__ Wa,
                            const float* __restrict__ Wt,
                            f16* __restrict__ x,
                            f16* __restrict__ dWb, f16* __restrict__ dWh) {
  const int blk = blockIdx.x;
  if (blk < 12288) {
    const int gid = blk * 256 + threadIdx.x;       // < 16384*192 exact
    const int per_row = CAT_ / 4;                  // 192
    int b = gid / per_row, j = gid - b * per_row;
    float4 v;
    if (j < IN_ / 4) v = ((const float4*)(inp + (size_t)b * IN_))[j];
    else             v = ((const float4*)(hx  + (size_t)b * HID_))[j - IN_ / 4];
    f16x4 o = {(f16)v.x, (f16)v.y, (f16)v.z, (f16)v.w};
    *((f16x4*)(x + (size_t)b * CAT_ + j * 4)) = o;
  } else if (blk < 13056) {
    const int i = (blk - 12288) * 256 + threadIdx.x;  // < 196608 exact
    float4 v = ((const float4*)Wb)[i];
    f16x4 o = {(f16)v.x, (f16)v.y, (f16)v.z, (f16)v.w};
    ((f16x4*)dWb)[i] = o;
  } else {
    const int i = (blk - 13056) * 256 + threadIdx.x;  // < 524288 exact
    const int np = i >> 8;                   // n' row in [0,2048)
    const int k4 = i & 255;
    const int h = (np >> 4) & 3;
    const int c = ((np >> 6) << 4) | (np & 15);
    const float* srcs[4] = {W1, W2, Wa, Wt};
    float4 v = *((const float4*)(srcs[h] + (size_t)c * UNITS_ + k4 * 4));
    f16x4 o = {(f16)v.x, (f16)v.y, (f16)v.z, (f16)v.w};
    *((f16x4*)(dWh + (size_t)np * UNITS_ + k4 * 4)) = o;
  }
}

// ---- shared GEMM geometry ----------------------------------------------
// Block: 256 thr / 4 waves (wr=wid>>1 row-half, wc=wid&1 col-half).
// Tile: 128 rows x 256 cols, BK=32. LDS: A 2x[128][32], B 2x[256][32].
// Staging (per 4KB call, r3-verified): thread t -> row t>>2 (64 rows/call),
// phys chunk t&3, source chunk (t&3)^((t>>3)&3). Read swizzle:
// phys chunk = klo ^ ((lane>>1)&3)  (row = 16a+fr => (row>>1)&3=(fr>>1)&3).

// ---- GEMM1: h = lecun_tanh(X @ Wb^T + bb) ------------------------------
// M=16384 N=1024 K=768. Grid 512: bid bits [2:0]=br&7, [4:3]=bc, [8:5]=br>>3.

__global__ __launch_bounds__(256, 2) void gemm1_kernel(
    const f16* __restrict__ X, const f16* __restrict__ Wb,
    const float* __restrict__ bb, f16* __restrict__ H) {
  constexpr int K = CAT_, BK = 32, NT = K / BK;  // 24
  __shared__ f16 As[2][128 * 32];  // 8 KB each
  __shared__ f16 Bs[2][256 * 32];  // 16 KB each
  const int t = threadIdx.x;
  const int lane = t & 63, wid = t >> 6;
  const int wr = wid >> 1, wc = wid & 1;
  const int bc = (blockIdx.x >> 3) & 3;
  const int br = (blockIdx.x >> 5) * 8 + (blockIdx.x & 7);
  const int arow0 = br * 128;
  const int bn0 = bc * 256;

  f32x4 acc[4][8] = {};  // [m][n]

  const int srow = t >> 2;                          // 0..63
  const int sch = ((t & 3) ^ ((t >> 3) & 3)) * 8;   // r3-verified
  const f16* aSrc = X + (size_t)(arow0 + srow) * K + sch;
  const f16* bSrc = Wb + (size_t)(bn0 + srow) * K + sch;
  const int l8 = t * 8;

  const int fr = lane & 15, klo = lane >> 4;
  const int cs = (klo ^ ((lane >> 1) & 3)) * 8;     // r3-verified

#define SA(d, q, kt) gload_lds16(aSrc + (size_t)(q) * 64 * K + (kt) * BK, &As[d][(q) * 2048 + l8])
#define SB(d, q, kt) gload_lds16(bSrc + (size_t)(q) * 64 * K + (kt) * BK, &Bs[d][(q) * 2048 + l8])

  SA(0, 0, 0); SA(0, 1, 0);
  SB(0, 0, 0); SB(0, 1, 0); SB(0, 2, 0); SB(0, 3, 0);
  asm volatile("s_waitcnt vmcnt(0)" ::: "memory");
  BARRIER();

  for (int tt = 0; tt < NT; ++tt) {
    const int cur = tt & 1, nxt = cur ^ 1;
    const int ktn = tt + 1;
    const bool more = (ktn < NT);
    f16x8 a[4], b[8];
#pragma unroll
    for (int m = 0; m < 4; ++m)
      a[m] = *((const f16x8*)(&As[cur][(wr * 64 + m * 16 + fr) * 32 + cs]));
#pragma unroll
    for (int n = 0; n < 4; ++n)
      b[n] = *((const f16x8*)(&Bs[cur][(wc * 128 + n * 16 + fr) * 32 + cs]));
    if (more) {
      SA(nxt, 0, ktn); SA(nxt, 1, ktn);
      SB(nxt, 0, ktn); SB(nxt, 1, ktn); SB(nxt, 2, ktn); SB(nxt, 3, ktn);
    }
    __builtin_amdgcn_s_setprio(1);
#pragma unroll
    for (int m = 0; m < 4; ++m)
#pragma unroll
      for (int n = 0; n < 4; ++n)
        acc[m][n] = MFMA16(a[m], b[n], acc[m][n]);
    __builtin_amdgcn_s_setprio(0);
#pragma unroll
    for (int n = 0; n < 4; ++n)
      b[4 + n] = *((const f16x8*)(&Bs[cur][(wc * 128 + 64 + n * 16 + fr) * 32 + cs]));
    __builtin_amdgcn_s_setprio(1);
#pragma unroll
    for (int m = 0; m < 4; ++m)
#pragma unroll
      for (int n = 0; n < 4; ++n)
        acc[m][4 + n] = MFMA16(a[m], b[4 + n], acc[m][4 + n]);
    __builtin_amdgcn_s_setprio(0);
    if (more) {
      asm volatile("s_waitcnt vmcnt(0)" ::: "memory");
      BARRIER();
    }
  }
#undef SA
#undef SB

#pragma unroll
  for (int n = 0; n < 8; ++n) {
    const int colg = bn0 + wc * 128 + (n >> 2) * 64 + (n & 3) * 16 + fr;
    const float bias = bb[colg];
#pragma unroll
    for (int m = 0; m < 4; ++m)
#pragma unroll
      for (int i = 0; i < 4; ++i) {
        const int rowg = arow0 + wr * 64 + m * 16 + klo * 4 + i;
        float v = acc[m][(n >> 2) * 4 + (n & 3)][i] + bias;
        v = 1.7159f * fast_tanh(0.666f * v);
        H[(size_t)rowg * UNITS_ + colg] = (f16)v;
      }
  }
}

// ---- GEMM2: four heads fused, same core ---------------------------------
// M=16384 N'=2048 K=1024. Grid 1024: bid bits [2:0]=br&7, [5:3]=bc,
// [9:6]=br>>3. Wave covers n' = bn0 + wc*128 + n*16 + fr; head = n&3,
// col-set = n>>2; HID col = (bc*4 + wc*2 + (n>>2))*16 + fr.

__global__ __launch_bounds__(256, 2) void gemm2_kernel(
    const f16* __restrict__ Hm, const f16* __restrict__ Wp,
    const float* __restrict__ b1, const float* __restrict__ b2,
    const float* __restrict__ ba, const float* __restrict__ bt,
    const float* __restrict__ ts, float* __restrict__ out) {
  constexpr int K = UNITS_, BK = 32, NT = K / BK;  // 32
  __shared__ f16 As[2][128 * 32];
  __shared__ f16 Bs[2][256 * 32];
  const int t = threadIdx.x;
  const int lane = t & 63, wid = t >> 6;
  const int wr = wid >> 1, wc = wid & 1;
  const int bc = (blockIdx.x >> 3) & 7;
  const int br = (blockIdx.x >> 6) * 8 + (blockIdx.x & 7);
  const int arow0 = br * 128;
  const int bn0 = bc * 256;

  f32x4 acc[4][8] = {};  // [m][n]  (n: head = n&3, set = n>>2)

  const int srow = t >> 2;
  const int sch = ((t & 3) ^ ((t >> 3) & 3)) * 8;
  const f16* aSrc = Hm + (size_t)(arow0 + srow) * K + sch;
  const f16* bSrc = Wp + (size_t)(bn0 + srow) * K + sch;
  const int l8 = t * 8;

  const int fr = lane & 15, klo = lane >> 4;
  const int cs = (klo ^ ((lane >> 1) & 3)) * 8;

#define SA(d, q, kt) gload_lds16(aSrc + (size_t)(q) * 64 * K + (kt) * BK, &As[d][(q) * 2048 + l8])
#define SB(d, q, kt) gload_lds16(bSrc + (size_t)(q) * 64 * K + (kt) * BK, &Bs[d][(q) * 2048 + l8])

  SA(0, 0, 0); SA(0, 1, 0);
  SB(0, 0, 0); SB(0, 1, 0); SB(0, 2, 0); SB(0, 3, 0);
  asm volatile("s_waitcnt vmcnt(0)" ::: "memory");
  BARRIER();

  for (int tt = 0; tt < NT; ++tt) {
    const int cur = tt & 1, nxt = cur ^ 1;
    const int ktn = tt + 1;
    const bool more = (ktn < NT);
    f16x8 a[4], b[8];
#pragma unroll
    for (int m = 0; m < 4; ++m)
      a[m] = *((const f16x8*)(&As[cur][(wr * 64 + m * 16 + fr) * 32 + cs]));
#pragma unroll
    for (int n = 0; n < 4; ++n)
      b[n] = *((const f16x8*)(&Bs[cur][(wc * 128 + n * 16 + fr) * 32 + cs]));
    if (more) {
      SA(nxt, 0, ktn); SA(nxt, 1, ktn);
      SB(nxt, 0, ktn); SB(nxt, 1, ktn); SB(nxt, 2, ktn); SB(nxt, 3, ktn);
    }
    __builtin_amdgcn_s_setprio(1);
#pragma unroll
    for (int m = 0; m < 4; ++m)
#pragma unroll
      for (int n = 0; n < 4; ++n)
        acc[m][n] = MFMA16(a[m], b[n], acc[m][n]);
    __builtin_amdgcn_s_setprio(0);
#pragma unroll
    for (int n = 0; n < 4; ++n)
      b[4 + n] = *((const f16x8*)(&Bs[cur][(wc * 128 + 64 + n * 16 + fr) * 32 + cs]));
    __builtin_amdgcn_s_setprio(1);
#pragma unroll
    for (int m = 0; m < 4; ++m)
#pragma unroll
      for (int n = 0; n < 4; ++n)
        acc[m][4 + n] = MFMA16(a[m], b[4 + n], acc[m][4 + n]);
    __builtin_amdgcn_s_setprio(0);
    if (more) {
      asm volatile("s_waitcnt vmcnt(0)" ::: "memory");
      BARRIER();
    }
  }
#undef SA
#undef SB

  // epilogue: acc[m][s*4+h] -> HID col (bc*4 + wc*2 + s)*16 + fr
#pragma unroll
  for (int s = 0; s < 2; ++s) {
    const int colg = (bc * 4 + wc * 2 + s) * 16 + fr;  // 0..511
    const float B1 = b1[colg], B2 = b2[colg], BA = ba[colg], BT = bt[colg];
#pragma unroll
    for (int m = 0; m < 4; ++m)
#pragma unroll
      for (int i = 0; i < 4; ++i) {
        const int rowg = arow0 + wr * 64 + m * 16 + klo * 4 + i;
        const float ff1 = fast_tanh(acc[m][s * 4 + 0][i] + B1);
        const float ff2 = fast_tanh(acc[m][s * 4 + 1][i] + B2);
        const float ta = acc[m][s * 4 + 2][i] + BA;
        const float tb = acc[m][s * 4 + 3][i] + BT;
        const float z = ta * ts[rowg] + tb;
        const float ti = 1.0f / (1.0f + __expf(-z));
        out[(size_t)rowg * HID_ + colg] = ff1 + ti * (ff2 - ff1);
      }
  }
}

// ---- launch -------------------------------------------------------------

extern "C" void kernel_launch(void* const* d_in, const int* in_sizes, int n_in,
                              void* d_out, int out_size, void* d_ws, size_t ws_size,
                              hipStream_t stream) {
  const float* input = (const float*)d_in[0];
  const float* hx    = (const float*)d_in[1];
  const float* ts    = (const float*)d_in[2];
  const float* Wb    = (const float*)d_in[3];
  const float* bb    = (const float*)d_in[4];
  const float* W1    = (const float*)d_in[5];
  const float* b1    = (const float*)d_in[6];
  const float* W2    = (const float*)d_in[7];
  const float* b2    = (const float*)d_in[8];
  const float* Wa    = (const float*)d_in[9];
  const float* ba    = (const float*)d_in[10];
  const float* Wt    = (const float*)d_in[11];
  const float* bt    = (const float*)d_in[12];
  float* out = (float*)d_out;

  char* ws = (char*)d_ws;
  f16* x_f16  = (f16*)ws;  ws += (size_t)B_ * CAT_ * 2;
  f16* h_f16  = (f16*)ws;  ws += (size_t)B_ * UNITS_ * 2;
  f16* Wb_f16 = (f16*)ws;  ws += (size_t)UNITS_ * CAT_ * 2;
  f16* Wh_f16 = (f16*)ws;  ws += (size_t)4 * HID_ * UNITS_ * 2;

  prep_kernel<<<dim3(15104), 256, 0, stream>>>(input, hx, Wb, W1, W2, Wa, Wt,
                                               x_f16, Wb_f16, Wh_f16);
  gemm1_kernel<<<dim3(512), 256, 0, stream>>>(x_f16, Wb_f16, bb, h_f16);
  gemm2_kernel<<<dim3(1024), 256, 0, stream>>>(h_f16, Wh_f16, b1, b2, ba, bt, ts, out);
}